// Round 7
// baseline (280.155 us; speedup 1.0000x reference)
//
#include <hip/hip_runtime.h>

#define T_LEN 131072
#define KDIM 128
#define CHUNK 128
#define WARM 16
#define NSTEP (CHUNK + WARM)
#define NCHUNK 1024   // ceil(131071/128); 4 pipes/block -> 256 blocks = 1/CU

typedef _Float16 h2 __attribute__((ext_vector_type(2)));

#if defined(__has_builtin)
#  if __has_builtin(__builtin_amdgcn_fdot2)
#    define HAVE_FDOT2 1
#  endif
#endif

__device__ __forceinline__ h2 u2h(unsigned u) { union U { unsigned u; h2 h; }; U x; x.u = u; return x.h; }
__device__ __forceinline__ unsigned h2u(h2 h) { union U { unsigned u; h2 h; }; U x; x.h = h; return x.u; }

__device__ __forceinline__ float dot2acc(h2 a, h2 b, float c) {
#ifdef HAVE_FDOT2
    return __builtin_amdgcn_fdot2(a, b, c, false);
#else
    c = fmaf((float)a.x, (float)b.x, c);
    return fmaf((float)a.y, (float)b.y, c);
#endif
}

__device__ __forceinline__ int trans_idx(int w2w, int ic, int dist) {
    return (w2w == 1) ? 0 : (ic == 0 ? 1 : (dist == 0 ? 2 : 3));
}

// ---- gold (+ fused idxArr prep): parallel gather + reduce ----
__global__ void gold_kernel(const float* __restrict__ em, const float* __restrict__ trans,
                            const float* __restrict__ start, const float* __restrict__ cw,
                            const int* __restrict__ tags, const int* __restrict__ w2w,
                            const int* __restrict__ ic, const int* __restrict__ dist,
                            unsigned char* __restrict__ idxArr, double* __restrict__ gold_acc) {
    int tid = blockIdx.x * blockDim.x + threadIdx.x;
    int stride = gridDim.x * blockDim.x;
    float part = 0.f;
    for (int t = tid; t < T_LEN; t += stride) {
        int tg = tags[t];
        float wt = cw[tg];
        float emv = em[(size_t)t * KDIM + tg];
        if (t == 0) {
            part += wt * (start[tg] + emv);
        } else {
            int m = trans_idx(w2w[t - 1], ic[t - 1], dist[t - 1]);
            idxArr[t - 1] = (unsigned char)m;
            int tgp = tags[t - 1];
            part += wt * (trans[((size_t)m * KDIM + tgp) * KDIM + tg] + emv);
        }
    }
    __shared__ float red[256];
    red[threadIdx.x] = part;
    __syncthreads();
    for (int s = 128; s > 0; s >>= 1) {
        if (threadIdx.x < (unsigned)s) red[threadIdx.x] += red[threadIdx.x + s];
        __syncthreads();
    }
    if (threadIdx.x == 0) atomicAdd(gold_acc, (double)red[0]);
}

// ---- scan: 1024 threads = 4 chunk-pipelines sharing one f16 LDS copy of all 4 E ----
// EL dword index = m*8192 + kp*1024 + tau*4 + j : half2(exp(tr[m][i][4p+j]), exp(tr[m][i+1][4p+j]))
// with i = 16*(tau>>5) + 2*kp, p = tau&31.  Lane's step data = 8 contiguous-16B chunks, stride 4KB.
// NOTE: v is renormalized EVERY step (lazily, by previous step's sum) so its
// entries stay within f16 range [~5e-3, ~1.4e4] — do not re-introduce skipped norms.
__global__ void __launch_bounds__(1024, 4) scan_kernel(
    const float* __restrict__ em, const float* __restrict__ trans,
    const unsigned char* __restrict__ idxArr, const float* __restrict__ start,
    double* __restrict__ logz_acc)
{
    const int pipe = threadIdx.x >> 8;      // 0..3
    const int tau  = threadIdx.x & 255;     // pipeline-local thread id
    const int c    = (blockIdx.x << 2) | pipe;
    const int p    = tau & 31;   // column group: cols 4p..4p+3
    const int h    = tau >> 5;   // i-group: i in [16h, 16h+16)

    __shared__ unsigned EL[32768];                       // 128 KB f16 E, shared by all pipes
    __shared__ unsigned v16[4][64];                      // v as half2 i-pairs, per pipe
    __shared__ __align__(16) float partial[4][8][KDIM];  // 16 KB
    __shared__ float wsum[4][2];

    // ---- stage: exponentiate trans -> f16 pairs in LDS (one-time, whole block) ----
    #pragma unroll
    for (int w = 0; w < 8; ++w) {
        const int dbase = (w << 12) + (threadIdx.x << 2);   // dword index of this uint4
        const int m  = dbase >> 13;
        const int r  = dbase & 8191;
        const int kp = r >> 10;
        const int L  = (r >> 2) & 255;
        const int i  = ((L >> 5) << 4) + (kp << 1);
        const float* tr0 = trans + ((size_t)m << 14) + (i << 7) + ((L & 31) << 2);
        unsigned o[4];
        #pragma unroll
        for (int j = 0; j < 4; ++j) {
            h2 hh;
            hh.x = (_Float16)__expf(tr0[j]);
            hh.y = (_Float16)__expf(tr0[j + KDIM]);
            o[j] = h2u(hh);
        }
        uint4 v4o; v4o.x = o[0]; v4o.y = o[1]; v4o.z = o[2]; v4o.w = o[3];
        *reinterpret_cast<uint4*>(&EL[dbase]) = v4o;
    }

    const int t_own = 1 + c * CHUNK;
    const int t_end = min(t_own + CHUNK, T_LEN);
    const int t0    = (c == 0) ? 1 : (t_own - WARM);

    // ---- init v ----
    float myv = 0.f;
    if (tau < KDIM) {
        myv = (c == 0) ? __expf(start[tau] + em[tau]) : 1.0f;
        float other = __shfl_xor(myv, 1, 64);
        if (!(tau & 1)) {
            h2 hh; hh.x = (_Float16)myv; hh.y = (_Float16)other;
            v16[pipe][tau >> 1] = h2u(hh);
        }
    }
    float r0 = myv;
    #pragma unroll
    for (int off = 32; off; off >>= 1) r0 += __shfl_down(r0, off, 64);
    if (tau < KDIM && (tau & 63) == 0) wsum[pipe][tau >> 6] = r0;
    __syncthreads();   // covers EL staging + v16 init + wsum
    const float s0 = wsum[pipe][0] + wsum[pipe][1];
    float scale = 1.0f / s0;

    float g = 0.f;
    if (c == 0 && tau == 0) g = __logf(s0);

    // ---- scalar/emission prefetch for step t0 ----
    int   pm = idxArr[t0 - 1];
    float em_pref = (tau < KDIM) ? em[(size_t)t0 * KDIM + tau] : 0.f;

    for (int it = 0; it < NSTEP; ++it) {
        const int t = t0 + it;
        const bool live = (t < t_end);
        const int m = pm;
        const float d = __expf(em_pref);

        // prefetch next step's scalars + emission row (clamped in-bounds)
        const int tn = min(t + 1, T_LEN - 1);
        pm = idxArr[tn - 1];
        if (tau < KDIM) em_pref = em[(size_t)tn * KDIM + tau];

        // phase 1: 64 MACs as 32 dot2 from f16 LDS
        const unsigned* Ep = EL + (m << 13) + (tau << 2);
        const unsigned* vp = &v16[pipe][h << 3];
        const uint4 va = *reinterpret_cast<const uint4*>(vp);
        const uint4 vb = *reinterpret_cast<const uint4*>(vp + 4);
        const unsigned vparr[8] = {va.x, va.y, va.z, va.w, vb.x, vb.y, vb.z, vb.w};
        float a0 = 0.f, a1 = 0.f, a2 = 0.f, a3 = 0.f;
        #pragma unroll
        for (int kp = 0; kp < 8; ++kp) {
            const uint4 e4 = *reinterpret_cast<const uint4*>(Ep + (kp << 10));
            const h2 vv = u2h(vparr[kp]);
            a0 = dot2acc(vv, u2h(e4.x), a0);
            a1 = dot2acc(vv, u2h(e4.y), a1);
            a2 = dot2acc(vv, u2h(e4.z), a2);
            a3 = dot2acc(vv, u2h(e4.w), a3);
        }
        *reinterpret_cast<float4*>(&partial[pipe][h][p << 2]) = make_float4(a0, a1, a2, a3);
        __syncthreads();

        // phase 2: combine 8 partials, apply emission + previous step's scale,
        // repack v to f16 pairs, reduce sum (EVERY step — f16 range safety)
        float tot = 0.f;
        if (tau < KDIM) {
            tot = (partial[pipe][0][tau] + partial[pipe][1][tau] + partial[pipe][2][tau] + partial[pipe][3][tau] +
                   partial[pipe][4][tau] + partial[pipe][5][tau] + partial[pipe][6][tau] + partial[pipe][7][tau]) * (d * scale);
            float other = __shfl_xor(tot, 1, 64);
            if (live && !(tau & 1)) {
                h2 hh; hh.x = (_Float16)tot; hh.y = (_Float16)other;
                v16[pipe][tau >> 1] = h2u(hh);
            }
        }
        float r = tot;
        #pragma unroll
        for (int off = 32; off; off >>= 1) r += __shfl_down(r, off, 64);
        if (tau < KDIM && (tau & 63) == 0) wsum[pipe][tau >> 6] = r;
        __syncthreads();

        const float s = wsum[pipe][0] + wsum[pipe][1];
        scale = 1.0f / s;
        if (tau == 0 && t >= t_own && t < t_end) g += __logf(s);
    }

    if (tau == 0) atomicAdd(logz_acc, (double)g);
}

__global__ void finalize_kernel(const double* __restrict__ acc, float* __restrict__ out) {
    if (threadIdx.x == 0 && blockIdx.x == 0) {
        out[0] = (float)acc[0];
        out[1] = (float)acc[1];
    }
}

extern "C" void kernel_launch(void* const* d_in, const int* in_sizes, int n_in,
                              void* d_out, int out_size, void* d_ws, size_t ws_size,
                              hipStream_t stream) {
    const float* emissions = (const float*)d_in[0];
    const float* trans     = (const float*)d_in[1];
    const float* start     = (const float*)d_in[2];
    const float* cw        = (const float*)d_in[3];
    const int*   tags      = (const int*)d_in[4];
    const int*   w2w       = (const int*)d_in[5];
    const int*   icnt      = (const int*)d_in[6];
    const int*   dist      = (const int*)d_in[7];

    double*        accs   = (double*)d_ws;                 // [0]=gold, [1]=logz
    unsigned char* idxArr = (unsigned char*)d_ws + 64;     // T-1 bytes

    hipMemsetAsync(d_ws, 0, 16, stream);
    gold_kernel<<<512, 256, 0, stream>>>(emissions, trans, start, cw, tags, w2w, icnt, dist, idxArr, &accs[0]);
    scan_kernel<<<NCHUNK / 4, 1024, 0, stream>>>(emissions, trans, idxArr, start, &accs[1]);
    finalize_kernel<<<1, 64, 0, stream>>>(accs, (float*)d_out);
}